// Round 1
// baseline (585.020 us; speedup 1.0000x reference)
//
#include <hip/hip_runtime.h>

// HyperspectralAttention collapses algebraically: with DIM==HEADS==64,
// c_per_head==1, so attn_spec/attn_spat are (B,64,1,1) and softmax over a
// singleton axis == 1.0 exactly. out = 0.6*v_spec + 0.4*v_spat, then proj.
//   y[b,o,p] = sum_c wproj[o,c] * illu[b,c,p] * (sum_i wmix[c,i]*x[b,i,p])
//   wmix = 0.6*w_v_spec + 0.4*w_v_spat
// q/k/anchor convs, temps, resizes are all dead code.

#define HW 65536   // 256*256
#define CH 64
#define NB 4

// Prep: blend wmix into ws[0..4095], transpose wproj into ws[4096..8191]
// (wprojT[c*64+o] = wproj[o*64+c]) so the main kernel's inner loops read
// contiguous, lane-uniform rows -> s_load_dwordx16 into SGPRs.
__global__ __launch_bounds__(256) void prep_weights(
    const float* __restrict__ wvs, const float* __restrict__ wvt,
    const float* __restrict__ wproj, float* __restrict__ ws) {
  int j = blockIdx.x * blockDim.x + threadIdx.x;
  if (j < CH * CH) {
    ws[j] = 0.6f * wvs[j] + 0.4f * wvt[j];
    int o = j >> 6, c = j & 63;
    ws[CH * CH + c * CH + o] = wproj[j];
  }
}

// One thread per pixel. xr[64] and acc[64] live in registers (inner loops
// fully unrolled => constant indexing => register promotion). Outer c-loop
// stays rolled (~1KB body) to avoid streaming 70KB of straight-line code
// through the 32KB I$. Weight reads are wave-uniform -> scalar loads.
__global__ __launch_bounds__(256) void fused_hsattn(
    const float* __restrict__ x, const float* __restrict__ illu,
    const float* __restrict__ ws, float* __restrict__ out) {
  const float* __restrict__ wmix   = ws;
  const float* __restrict__ wprojT = ws + CH * CH;

  int tid = blockIdx.x * blockDim.x + threadIdx.x;  // 0 .. 262143
  int pix = tid & (HW - 1);
  int b   = tid >> 16;
  int base = b * CH * HW + pix;   // max 16,777,215: fits int

  // Load this pixel's 64-channel x vector. Lane i -> pix i: coalesced.
  float xr[CH];
#pragma unroll
  for (int i = 0; i < CH; ++i) xr[i] = x[base + i * HW];

  float acc[CH];
#pragma unroll
  for (int o = 0; o < CH; ++o) acc[o] = 0.f;

  for (int c = 0; c < CH; ++c) {
    const float* __restrict__ wr = wmix + c * CH;
    // 4-way split dot: breaks the 64-deep FMA dependence chain.
    float t0 = 0.f, t1 = 0.f, t2 = 0.f, t3 = 0.f;
#pragma unroll
    for (int i = 0; i < CH; i += 4) {
      t0 = fmaf(wr[i + 0], xr[i + 0], t0);
      t1 = fmaf(wr[i + 1], xr[i + 1], t1);
      t2 = fmaf(wr[i + 2], xr[i + 2], t2);
      t3 = fmaf(wr[i + 3], xr[i + 3], t3);
    }
    float u = illu[base + c * HW] * ((t0 + t1) + (t2 + t3));

    const float* __restrict__ pr = wprojT + c * CH;
#pragma unroll
    for (int o = 0; o < CH; ++o) acc[o] = fmaf(pr[o], u, acc[o]);
  }

#pragma unroll
  for (int o = 0; o < CH; ++o) out[base + o * HW] = acc[o];
}

extern "C" void kernel_launch(void* const* d_in, const int* in_sizes, int n_in,
                              void* d_out, int out_size, void* d_ws, size_t ws_size,
                              hipStream_t stream) {
  const float* x     = (const float*)d_in[0];   // (4,64,256,256)
  const float* illu  = (const float*)d_in[1];   // (4,64,256,256)
  const float* wvs   = (const float*)d_in[4];   // w_v_spec (64,64)
  const float* wvt   = (const float*)d_in[7];   // w_v_spat (64,64)
  const float* wproj = (const float*)d_in[10];  // w_proj   (64,64)
  float* out = (float*)d_out;
  float* ws  = (float*)d_ws;   // needs 8192 floats = 32 KB

  prep_weights<<<(CH * CH + 255) / 256, 256, 0, stream>>>(wvs, wvt, wproj, ws);

  int n_pix = NB * HW;                       // 262144
  fused_hsattn<<<n_pix / 256, 256, 0, stream>>>(x, illu, ws, out);
}

// Round 2
// 206.741 us; speedup vs baseline: 2.8297x; 2.8297x over previous
//
#include <hip/hip_runtime.h>

// HyperspectralAttention collapses algebraically (DIM==HEADS==64 =>
// c_per_head==1 => softmax over singleton axis == 1.0):
//   y[b,o,p] = sum_c wproj[o,c] * illu[b,c,p] * (sum_i wmix[c,i]*x[b,i,p])
//   wmix = 0.6*w_v_spec + 0.4*w_v_spat
//
// R2 structure: fused double-GEMM, register-tiled. Block=256 threads owns a
// 64-pixel tile. Lane owns 4 channels x 4 pixels (16 accumulators) per phase.
// x-tile and u-intermediate share one LDS buffer; weights staged per-phase
// into a second. Inner loop: 2x ds_read_b128 + 16 FMA -> compute-bound.
// (R1: 128 regs/thread -> no pipelining headroom, SGPR weight reloads every
// iter, latency-bound at 453us / 7% VALUBusy.)

#define HW 65536   // 256*256
#define CH 64
#define NB 4
#define PT 64      // pixels per block tile
#define XS 68      // padded LDS stride for xu_s (breaks c-row bank aliasing)

// ws[0..4095]    = wmixT[i*64+c]  (transposed blend)
// ws[4096..8191] = wprojT[c*64+o] (transposed proj)
__global__ __launch_bounds__(256) void prep_weights(
    const float* __restrict__ wvs, const float* __restrict__ wvt,
    const float* __restrict__ wproj, float* __restrict__ ws) {
  int j = blockIdx.x * blockDim.x + threadIdx.x;
  if (j < CH * CH) {
    int r = j >> 6, q = j & 63;               // j = r*64 + q
    ws[q * CH + r] = 0.6f * wvs[j] + 0.4f * wvt[j];   // wmixT[i][c], r=c q=i
    ws[CH * CH + q * CH + r] = wproj[j];              // wprojT[c][o], r=o q=c
  }
}

#define FMA16(A, wq, vq)                                        \
  A##00 = fmaf(wq.x, vq.x, A##00); A##01 = fmaf(wq.x, vq.y, A##01); \
  A##02 = fmaf(wq.x, vq.z, A##02); A##03 = fmaf(wq.x, vq.w, A##03); \
  A##10 = fmaf(wq.y, vq.x, A##10); A##11 = fmaf(wq.y, vq.y, A##11); \
  A##12 = fmaf(wq.y, vq.z, A##12); A##13 = fmaf(wq.y, vq.w, A##13); \
  A##20 = fmaf(wq.z, vq.x, A##20); A##21 = fmaf(wq.z, vq.y, A##21); \
  A##22 = fmaf(wq.z, vq.z, A##22); A##23 = fmaf(wq.z, vq.w, A##23); \
  A##30 = fmaf(wq.w, vq.x, A##30); A##31 = fmaf(wq.w, vq.y, A##31); \
  A##32 = fmaf(wq.w, vq.z, A##32); A##33 = fmaf(wq.w, vq.w, A##33)

__global__ __launch_bounds__(256) void fused_hsattn(
    const float* __restrict__ x, const float* __restrict__ illu,
    const float* __restrict__ ws, float* __restrict__ out) {
  __shared__ float w_s[CH * CH];    // 16 KB: wmixT, then wprojT
  __shared__ float xu_s[CH * XS];   // 17 KB: x[i][p], then u[c][p]

  const int tid  = threadIdx.x;
  const int t    = blockIdx.x;
  const int b    = t >> 10;                   // HW/PT = 1024 tiles per batch
  const int pix0 = (t & 1023) << 6;
  const int bx   = b * CH * HW + pix0;        // max ~16.7M, fits int

  // ---- stage x tile + wmixT (float4, fully coalesced) ----
#pragma unroll
  for (int k = 0; k < 4; ++k) {
    int flat = k * 1024 + tid * 4;            // 0..4095
    int i = flat >> 6, p = flat & 63;
    *(float4*)&xu_s[i * XS + p] = *(const float4*)&x[bx + i * HW + p];
    *(float4*)&w_s[flat]        = *(const float4*)&ws[flat];
  }
  __syncthreads();

  const int lane = tid & 63;
  const int p0 = (lane & 15) << 2;                       // 4-pixel group
  const int co = ((tid >> 6) << 4) + ((lane >> 4) << 2); // 4-channel group

  // ---- phase 2: u[co..co+3][p0..p0+3] = wmix * x ----
  float a00=0,a01=0,a02=0,a03=0, a10=0,a11=0,a12=0,a13=0,
        a20=0,a21=0,a22=0,a23=0, a30=0,a31=0,a32=0,a33=0;
#pragma unroll 8
  for (int i = 0; i < CH; ++i) {
    const float4 xq = *(const float4*)&xu_s[i * XS + p0];  // 2-way alias: free
    const float4 wq = *(const float4*)&w_s[i * CH + co];   // 16-lane broadcast
    FMA16(a, wq, xq);
  }

  // ---- illu gate (coalesced float4 per channel row) ----
  const float4 il0 = *(const float4*)&illu[bx + (co + 0) * HW + p0];
  const float4 il1 = *(const float4*)&illu[bx + (co + 1) * HW + p0];
  const float4 il2 = *(const float4*)&illu[bx + (co + 2) * HW + p0];
  const float4 il3 = *(const float4*)&illu[bx + (co + 3) * HW + p0];

  __syncthreads();   // everyone done reading x-tile and wmixT

  // ---- write u into xu_s; stage wprojT over w_s ----
  *(float4*)&xu_s[(co + 0) * XS + p0] = make_float4(a00*il0.x, a01*il0.y, a02*il0.z, a03*il0.w);
  *(float4*)&xu_s[(co + 1) * XS + p0] = make_float4(a10*il1.x, a11*il1.y, a12*il1.z, a13*il1.w);
  *(float4*)&xu_s[(co + 2) * XS + p0] = make_float4(a20*il2.x, a21*il2.y, a22*il2.z, a23*il2.w);
  *(float4*)&xu_s[(co + 3) * XS + p0] = make_float4(a30*il3.x, a31*il3.y, a32*il3.z, a33*il3.w);
#pragma unroll
  for (int k = 0; k < 4; ++k) {
    int flat = k * 1024 + tid * 4;
    *(float4*)&w_s[flat] = *(const float4*)&ws[CH * CH + flat];
  }
  __syncthreads();

  // ---- phase 3: y[co..co+3][p0..p0+3] = wproj * u ----
  float b00=0,b01=0,b02=0,b03=0, b10=0,b11=0,b12=0,b13=0,
        b20=0,b21=0,b22=0,b23=0, b30=0,b31=0,b32=0,b33=0;
#pragma unroll 8
  for (int c = 0; c < CH; ++c) {
    const float4 uq = *(const float4*)&xu_s[c * XS + p0];
    const float4 wq = *(const float4*)&w_s[c * CH + co];
    FMA16(b, wq, uq);
  }

  *(float4*)&out[bx + (co + 0) * HW + p0] = make_float4(b00, b01, b02, b03);
  *(float4*)&out[bx + (co + 1) * HW + p0] = make_float4(b10, b11, b12, b13);
  *(float4*)&out[bx + (co + 2) * HW + p0] = make_float4(b20, b21, b22, b23);
  *(float4*)&out[bx + (co + 3) * HW + p0] = make_float4(b30, b31, b32, b33);
}

extern "C" void kernel_launch(void* const* d_in, const int* in_sizes, int n_in,
                              void* d_out, int out_size, void* d_ws, size_t ws_size,
                              hipStream_t stream) {
  const float* x     = (const float*)d_in[0];   // (4,64,256,256)
  const float* illu  = (const float*)d_in[1];   // (4,64,256,256)
  const float* wvs   = (const float*)d_in[4];   // w_v_spec (64,64)
  const float* wvt   = (const float*)d_in[7];   // w_v_spat (64,64)
  const float* wproj = (const float*)d_in[10];  // w_proj   (64,64)
  float* out = (float*)d_out;
  float* ws  = (float*)d_ws;                    // 8192 floats = 32 KB

  prep_weights<<<(CH * CH + 255) / 256, 256, 0, stream>>>(wvs, wvt, wproj, ws);
  fused_hsattn<<<NB * (HW / PT), 256, 0, stream>>>(x, illu, ws, out);
}

// Round 4
// 201.571 us; speedup vs baseline: 2.9023x; 1.0256x over previous
//
#include <hip/hip_runtime.h>

// y[b,o,p] = sum_c wproj[o,c] * illu[b,c,p] * (sum_i wmix[c,i]*x[b,i,p])
// (attention collapses: DIM==HEADS==64 => c_per_head==1 => softmax over a
//  singleton axis == 1.0; q/k/anchor/temps/resizes are dead code)
//
// R4: SINGLE stateless kernel. R3's prep->d_ws->fused chain diverged on
// graph replay (0xAA-poisoned ws as bf16 ~= 0 => zeroed weights => absmax
// ~= max|ref|); weights are now read from d_in and blended in-kernel.
// Also: x-staging is line-per-thread (each 128B line fetched once, LDS
// transpose writes 2 lanes/bank = free), and lo-planes dropped (measured
// R3 absmax 1.95e-3 with them; predicted ~2.5e-3 without, thr 9.6e-3).
// LDS 34 KB -> 4 blocks/CU.

#define HW 65536
#define CH 64
#define PT 128   // pixels per block
#define SX 68    // LDS row stride (bf16): 136 B, 8B-aligned rows, bank-uniform

typedef short s4_t __attribute__((ext_vector_type(4)));
typedef short s8_t __attribute__((ext_vector_type(8)));
typedef float f4_t __attribute__((ext_vector_type(4)));

static __device__ __forceinline__ unsigned short f2bf(float f) {
  unsigned u = __float_as_uint(f);
  return (unsigned short)((u + 0x7fffu + ((u >> 16) & 1u)) >> 16);  // RNE
}
static __device__ __forceinline__ s8_t ld8(const unsigned short* p) {
  s4_t lo = *(const s4_t*)p;        // rows are 8B-aligned: 2x ds_read_b64
  s4_t hi = *(const s4_t*)(p + 4);
  s8_t r = {lo[0], lo[1], lo[2], lo[3], hi[0], hi[1], hi[2], hi[3]};
  return r;
}

__global__ __launch_bounds__(256, 4) void fused_hsattn(
    const float* __restrict__ x, const float* __restrict__ illu,
    const float* __restrict__ wvs, const float* __restrict__ wvt,
    const float* __restrict__ wproj, float* __restrict__ out) {
  __shared__ __align__(16) unsigned short XH[PT * SX];  // x^T then u'^T, [p][c]
  __shared__ __align__(16) unsigned short WM[CH * SX];  // wmix  [c][i]
  __shared__ __align__(16) unsigned short WP[CH * SX];  // wproj [o][c]

  const int tid  = threadIdx.x;
  const int bb   = blockIdx.x >> 9;            // 512 blocks per batch image
  const int pix0 = (blockIdx.x & 511) << 7;    // *128
  const int base = bb * CH * HW + pix0;        // max ~16.7M: fits int

  // ---- stage weights from global (48 KB fp32, L2/L3-shared across blocks)
#pragma unroll
  for (int it = 0; it < 4; ++it) {
    int idx = it * 256 + tid;                  // 0..1023 float4s
    int j4  = idx * 4;
    int row = idx >> 4, col = (idx & 15) * 4;
    f4_t a = *(const f4_t*)(wvs + j4);
    f4_t b = *(const f4_t*)(wvt + j4);
    f4_t p = *(const f4_t*)(wproj + j4);
    s4_t m, w;
#pragma unroll
    for (int j = 0; j < 4; ++j) {
      m[j] = (short)f2bf(0.6f * a[j] + 0.4f * b[j]);
      w[j] = (short)f2bf(p[j]);
    }
    *(s4_t*)(WM + row * SX + col) = m;
    *(s4_t*)(WP + row * SX + col) = w;
  }

  // ---- stage x transposed: thread owns (ch, 32-pixel) = one 128B line.
  // Line fetched once (7/8 loads L1-hit); b16 LDS writes: lanes 0..63 at
  // fixed (k,j) hit bank (34p + ch/2)&31 -> 32 banks x 2 lanes = free.
  {
    const int ch = tid & 63, ps = tid >> 6;    // ps 0..3
    const float* xp = x + base + ch * HW + ps * 32;
#pragma unroll
    for (int k = 0; k < 8; ++k) {
      f4_t v = *(const f4_t*)(xp + k * 4);
#pragma unroll
      for (int j = 0; j < 4; ++j)
        XH[(ps * 32 + k * 4 + j) * SX + ch] = f2bf(v[j]);
    }
  }
  __syncthreads();

  const int lane = tid & 63;
  const int wv   = tid >> 6;
  const int n15  = lane & 15, q = lane >> 4;
  const int nb   = wv * 32;                    // wave owns pixels nb..nb+31

  // ---- phase 1: u = wmix * x
  // A[m=lane&15][k=q*8+j] from WM; B[n=lane&15][k] from XH (m97 layout)
  f4_t acc[8];                                 // [mt*2+nt]
#pragma unroll
  for (int i = 0; i < 8; ++i) acc[i] = (f4_t){0.f, 0.f, 0.f, 0.f};
#pragma unroll
  for (int kc = 0; kc < 2; ++kc) {
    s8_t A[4];
#pragma unroll
    for (int mt = 0; mt < 4; ++mt)
      A[mt] = ld8(WM + (mt * 16 + n15) * SX + kc * 32 + q * 8);
#pragma unroll
    for (int nt = 0; nt < 2; ++nt) {
      s8_t B = ld8(XH + (nb + nt * 16 + n15) * SX + kc * 32 + q * 8);
#pragma unroll
      for (int mt = 0; mt < 4; ++mt)
        acc[mt * 2 + nt] =
            __builtin_amdgcn_mfma_f32_16x16x32_bf16(A[mt], B, acc[mt * 2 + nt], 0, 0, 0);
    }
  }

  // ---- gate by illu; C/D: row c = mt*16 + q*4 + r, col p = nb + nt*16 + n15
  s4_t uh[8];
#pragma unroll
  for (int mt = 0; mt < 4; ++mt)
#pragma unroll
    for (int nt = 0; nt < 2; ++nt) {
      const float* ip = illu + base + (mt * 16 + q * 4) * HW + nb + nt * 16 + n15;
      f4_t a = acc[mt * 2 + nt];
      s4_t h;
#pragma unroll
      for (int r = 0; r < 4; ++r) h[r] = (short)f2bf(a[r] * ip[r * HW]);
      uh[mt * 2 + nt] = h;
    }
  __syncthreads();   // (wave-local rows, but keep R3's proven barrier shape)

  // ---- write u'^T over X region ([p][c], b64 writes, bank-uniform)
#pragma unroll
  for (int mt = 0; mt < 4; ++mt)
#pragma unroll
    for (int nt = 0; nt < 2; ++nt)
      *(s4_t*)(XH + (nb + nt * 16 + n15) * SX + mt * 16 + q * 4) = uh[mt * 2 + nt];
  __syncthreads();

  // ---- phase 2: y = wproj * u'
  f4_t acc2[8];
#pragma unroll
  for (int i = 0; i < 8; ++i) acc2[i] = (f4_t){0.f, 0.f, 0.f, 0.f};
#pragma unroll
  for (int kc = 0; kc < 2; ++kc) {
    s8_t A[4];
#pragma unroll
    for (int mt = 0; mt < 4; ++mt)
      A[mt] = ld8(WP + (mt * 16 + n15) * SX + kc * 32 + q * 8);
#pragma unroll
    for (int nt = 0; nt < 2; ++nt) {
      s8_t B = ld8(XH + (nb + nt * 16 + n15) * SX + kc * 32 + q * 8);
#pragma unroll
      for (int mt = 0; mt < 4; ++mt)
        acc2[mt * 2 + nt] =
            __builtin_amdgcn_mfma_f32_16x16x32_bf16(A[mt], B, acc2[mt * 2 + nt], 0, 0, 0);
    }
  }

  // ---- store (C/D layout; 16-lane 64B segments, nt pair completes lines)
#pragma unroll
  for (int mt = 0; mt < 4; ++mt)
#pragma unroll
    for (int nt = 0; nt < 2; ++nt) {
      float* op = out + base + (mt * 16 + q * 4) * HW + nb + nt * 16 + n15;
      f4_t a = acc2[mt * 2 + nt];
#pragma unroll
      for (int r = 0; r < 4; ++r) op[r * HW] = a[r];
    }
}

extern "C" void kernel_launch(void* const* d_in, const int* in_sizes, int n_in,
                              void* d_out, int out_size, void* d_ws, size_t ws_size,
                              hipStream_t stream) {
  const float* x     = (const float*)d_in[0];   // (4,64,256,256)
  const float* illu  = (const float*)d_in[1];   // (4,64,256,256)
  const float* wvs   = (const float*)d_in[4];   // w_v_spec (64,64)
  const float* wvt   = (const float*)d_in[7];   // w_v_spat (64,64)
  const float* wproj = (const float*)d_in[10];  // w_proj   (64,64)
  float* out = (float*)d_out;

  fused_hsattn<<<4 * (HW / PT), 256, 0, stream>>>(x, illu, wvs, wvt, wproj, out);
}

// Round 5
// 199.100 us; speedup vs baseline: 2.9383x; 1.0124x over previous
//
#include <hip/hip_runtime.h>

// y[b,o,p] = sum_c wproj[o,c] * illu[b,c,p] * (sum_i wmix[c,i]*x[b,i,p])
// (attention collapses: DIM==HEADS==64 => c_per_head==1 => softmax over a
//  singleton axis == 1.0; q/k/anchor/temps/resizes are dead code)
//
// R5: single-burst loading. R4 was latency-bound (75us, VALU 7%, HBM 22%):
// VGPR=52 forced the compiler into load->wait->convert dribble (~2KB in
// flight/CU vs 9KB needed for the HBM floor), and the 32 mid-kernel illu
// scalar loads serialized after phase-1 MFMAs. Now ALL global reads (illu
// into registers, weights, x) issue in one burst before the first barrier
// (loads can't sink past __syncthreads) -> ~340KB/CU in flight. LB(256,3)
// gives ~168 VGPR so the ~112-reg burst doesn't spill. MFMA layouts and
// numerics identical to R4 (verified absmax 1.95e-3 vs 9.6e-3 threshold).

#define HW 65536
#define CH 64
#define PT 128   // pixels per block
#define SX 68    // LDS row stride (bf16): 136 B, 8B-aligned rows, bank-uniform

typedef short s4_t __attribute__((ext_vector_type(4)));
typedef short s8_t __attribute__((ext_vector_type(8)));
typedef float f4_t __attribute__((ext_vector_type(4)));

static __device__ __forceinline__ unsigned short f2bf(float f) {
  unsigned u = __float_as_uint(f);
  return (unsigned short)((u + 0x7fffu + ((u >> 16) & 1u)) >> 16);  // RNE
}
static __device__ __forceinline__ s8_t ld8(const unsigned short* p) {
  s4_t lo = *(const s4_t*)p;        // rows are 8B-aligned: 2x ds_read_b64
  s4_t hi = *(const s4_t*)(p + 4);
  s8_t r = {lo[0], lo[1], lo[2], lo[3], hi[0], hi[1], hi[2], hi[3]};
  return r;
}

__global__ __launch_bounds__(256, 3) void fused_hsattn(
    const float* __restrict__ x, const float* __restrict__ illu,
    const float* __restrict__ wvs, const float* __restrict__ wvt,
    const float* __restrict__ wproj, float* __restrict__ out) {
  __shared__ __align__(16) unsigned short XH[PT * SX];  // x^T then u'^T, [p][c]
  __shared__ __align__(16) unsigned short WM[CH * SX];  // wmix  [c][i]
  __shared__ __align__(16) unsigned short WP[CH * SX];  // wproj [o][c]

  const int tid  = threadIdx.x;
  const int bb   = blockIdx.x >> 9;            // 512 blocks per batch image
  const int pix0 = (blockIdx.x & 511) << 7;    // *128
  const int base = bb * CH * HW + pix0;        // max ~16.7M: fits int

  const int lane = tid & 63;
  const int wv   = tid >> 6;
  const int n15  = lane & 15, q = lane >> 4;
  const int nb   = wv * 32;                    // wave owns pixels nb..nb+31

  // ---- BURST 1: illu into registers (32 dwords). Needed only after
  // phase 1, but issued here so they ride the same latency window; they
  // cannot sink past the barrier. C/D layout: row c=mt*16+q*4+r, col
  // p=nb+nt*16+n15.
  float il[32];
#pragma unroll
  for (int mt = 0; mt < 4; ++mt)
#pragma unroll
    for (int nt = 0; nt < 2; ++nt) {
      const float* ip = illu + base + (mt * 16 + q * 4) * HW + nb + nt * 16 + n15;
#pragma unroll
      for (int r = 0; r < 4; ++r) il[(mt * 2 + nt) * 4 + r] = ip[r * HW];
    }

  // ---- BURST 2: weights (12x float4; L2/LLC-shared across 2048 blocks)
#pragma unroll
  for (int it = 0; it < 4; ++it) {
    int idx = it * 256 + tid;                  // 0..1023 float4s
    int j4  = idx * 4;
    int row = idx >> 4, col = (idx & 15) * 4;
    f4_t a = *(const f4_t*)(wvs + j4);
    f4_t b = *(const f4_t*)(wvt + j4);
    f4_t p = *(const f4_t*)(wproj + j4);
    s4_t m, w;
#pragma unroll
    for (int j = 0; j < 4; ++j) {
      m[j] = (short)f2bf(0.6f * a[j] + 0.4f * b[j]);
      w[j] = (short)f2bf(p[j]);
    }
    *(s4_t*)(WM + row * SX + col) = m;
    *(s4_t*)(WP + row * SX + col) = w;
  }

  // ---- BURST 3: x tile (8x float4/thread, thread owns one 128B line),
  // transposed into LDS [p][c]; b16 writes land 2 lanes/bank (free, m136).
  {
    const int ch = tid & 63, ps = tid >> 6;    // ps 0..3
    const float* xp = x + base + ch * HW + ps * 32;
    f4_t v[8];
#pragma unroll
    for (int k = 0; k < 8; ++k) v[k] = *(const f4_t*)(xp + k * 4);
#pragma unroll
    for (int k = 0; k < 8; ++k)
#pragma unroll
      for (int j = 0; j < 4; ++j)
        XH[(ps * 32 + k * 4 + j) * SX + ch] = f2bf(v[k][j]);
  }
  __syncthreads();

  // ---- phase 1: u = wmix * x
  // A[m=lane&15][k=q*8+j] from WM; B[n=lane&15][k] from XH (m97 layout)
  f4_t acc[8];                                 // [mt*2+nt]
#pragma unroll
  for (int i = 0; i < 8; ++i) acc[i] = (f4_t){0.f, 0.f, 0.f, 0.f};
#pragma unroll
  for (int kc = 0; kc < 2; ++kc) {
    s8_t A[4];
#pragma unroll
    for (int mt = 0; mt < 4; ++mt)
      A[mt] = ld8(WM + (mt * 16 + n15) * SX + kc * 32 + q * 8);
#pragma unroll
    for (int nt = 0; nt < 2; ++nt) {
      s8_t B = ld8(XH + (nb + nt * 16 + n15) * SX + kc * 32 + q * 8);
#pragma unroll
      for (int mt = 0; mt < 4; ++mt)
        acc[mt * 2 + nt] =
            __builtin_amdgcn_mfma_f32_16x16x32_bf16(A[mt], B, acc[mt * 2 + nt], 0, 0, 0);
    }
  }

  // ---- gate by resident illu registers (no global access here)
  s4_t uh[8];
#pragma unroll
  for (int mt = 0; mt < 4; ++mt)
#pragma unroll
    for (int nt = 0; nt < 2; ++nt) {
      f4_t a = acc[mt * 2 + nt];
      s4_t h;
#pragma unroll
      for (int r = 0; r < 4; ++r)
        h[r] = (short)f2bf(a[r] * il[(mt * 2 + nt) * 4 + r]);
      uh[mt * 2 + nt] = h;
    }
  __syncthreads();   // all waves done reading XH

  // ---- write u'^T over X region ([p][c], b64 writes, bank-uniform)
#pragma unroll
  for (int mt = 0; mt < 4; ++mt)
#pragma unroll
    for (int nt = 0; nt < 2; ++nt)
      *(s4_t*)(XH + (nb + nt * 16 + n15) * SX + mt * 16 + q * 4) = uh[mt * 2 + nt];
  __syncthreads();

  // ---- phase 2: y = wproj * u'
  f4_t acc2[8];
#pragma unroll
  for (int i = 0; i < 8; ++i) acc2[i] = (f4_t){0.f, 0.f, 0.f, 0.f};
#pragma unroll
  for (int kc = 0; kc < 2; ++kc) {
    s8_t A[4];
#pragma unroll
    for (int mt = 0; mt < 4; ++mt)
      A[mt] = ld8(WP + (mt * 16 + n15) * SX + kc * 32 + q * 8);
#pragma unroll
    for (int nt = 0; nt < 2; ++nt) {
      s8_t B = ld8(XH + (nb + nt * 16 + n15) * SX + kc * 32 + q * 8);
#pragma unroll
      for (int mt = 0; mt < 4; ++mt)
        acc2[mt * 2 + nt] =
            __builtin_amdgcn_mfma_f32_16x16x32_bf16(A[mt], B, acc2[mt * 2 + nt], 0, 0, 0);
    }
  }

  // ---- store (C/D layout; 16-lane 64B segments, nt pair completes lines)
#pragma unroll
  for (int mt = 0; mt < 4; ++mt)
#pragma unroll
    for (int nt = 0; nt < 2; ++nt) {
      float* op = out + base + (mt * 16 + q * 4) * HW + nb + nt * 16 + n15;
      f4_t a = acc2[mt * 2 + nt];
#pragma unroll
      for (int r = 0; r < 4; ++r) op[r * HW] = a[r];
    }
}

extern "C" void kernel_launch(void* const* d_in, const int* in_sizes, int n_in,
                              void* d_out, int out_size, void* d_ws, size_t ws_size,
                              hipStream_t stream) {
  const float* x     = (const float*)d_in[0];   // (4,64,256,256)
  const float* illu  = (const float*)d_in[1];   // (4,64,256,256)
  const float* wvs   = (const float*)d_in[4];   // w_v_spec (64,64)
  const float* wvt   = (const float*)d_in[7];   // w_v_spat (64,64)
  const float* wproj = (const float*)d_in[10];  // w_proj   (64,64)
  float* out = (float*)d_out;

  fused_hsattn<<<4 * (HW / PT), 256, 0, stream>>>(x, illu, wvs, wvt, wproj, out);
}

// Round 6
// 198.194 us; speedup vs baseline: 2.9518x; 1.0046x over previous
//
#include <hip/hip_runtime.h>

// y[b,o,p] = sum_c wproj[o,c] * illu[b,c,p] * (sum_i wmix[c,i]*x[b,i,p])
// (attention collapses: DIM==HEADS==64 => softmax over singleton == 1.0)
//
// R6: async global->LDS staging. R2/R4/R5 all pinned at ~75us (VALU 7%,
// HBM 22%, VGPR stuck at 56): the compiler serializes VGPR-path loads
// (load->vmcnt->convert dribble), capping memory-level parallelism. Fix per
// guide §5 mistake #1: __builtin_amdgcn_global_load_lds (no VGPR round-trip,
// fire-and-forget; m93->m97 = 1.69x). x/illu stage async in natural [c][p]
// fp32; LDS->LDS pass builds bf16 [p][c] B-operand layout. Weights (L2-hot)
// load via VGPR *before* the async burst so their vmcnt wait leaves the
// async queue in flight. PT=64 -> 58.9KB LDS -> 2 blocks/CU overlap.
// MFMA fragment indexing identical to R4/R5 (verified absmax 1.95e-3).

#define HW 65536
#define CH 64
#define PT 64    // pixels per block
#define SX 68    // bf16 row stride: 136B rows, 8B-aligned, bank-uniform frags

typedef short s4_t __attribute__((ext_vector_type(4)));
typedef short s8_t __attribute__((ext_vector_type(8)));
typedef float f4_t __attribute__((ext_vector_type(4)));

typedef const __attribute__((address_space(1))) unsigned int* gp_t;
typedef __attribute__((address_space(3))) unsigned int* lp_t;

static __device__ __forceinline__ unsigned short f2bf(float f) {
  unsigned u = __float_as_uint(f);
  return (unsigned short)((u + 0x7fffu + ((u >> 16) & 1u)) >> 16);  // RNE
}
static __device__ __forceinline__ s8_t ld8(const unsigned short* p) {
  s4_t lo = *(const s4_t*)p;        // rows 8B-aligned: 2x ds_read_b64
  s4_t hi = *(const s4_t*)(p + 4);
  s8_t r = {lo[0], lo[1], lo[2], lo[3], hi[0], hi[1], hi[2], hi[3]};
  return r;
}
// async 16B/lane global->LDS; lds base must be wave-uniform (lane scatters
// to base + lane*16). uintptr round-trip = the CK-blessed AS cast.
static __device__ __forceinline__ void gload16(const float* g, float* l) {
  __builtin_amdgcn_global_load_lds((gp_t)(unsigned long long)g,
                                   (lp_t)(unsigned long long)l, 16, 0, 0);
}

__global__ __launch_bounds__(256, 2) void fused_hsattn(
    const float* __restrict__ x, const float* __restrict__ illu,
    const float* __restrict__ wvs, const float* __restrict__ wvt,
    const float* __restrict__ wproj, float* __restrict__ out) {
  __shared__ __align__(16) float xs[CH * PT];            // 16 KB  x  [c][p]
  __shared__ __align__(16) float ils[CH * PT];           // 16 KB illu[c][p]
  __shared__ __align__(16) unsigned short XH[PT * SX];   // 8.5 KB x^T/u'^T bf16
  __shared__ __align__(16) unsigned short WM[CH * SX];   // 8.5 KB wmix  [c][i]
  __shared__ __align__(16) unsigned short WP[CH * SX];   // 8.5 KB wproj [o][c]

  const int tid  = threadIdx.x;
  const int bb   = blockIdx.x >> 10;           // 1024 blocks per batch image
  const int pix0 = (blockIdx.x & 1023) << 6;   // *64
  const int base = bb * CH * HW + pix0;        // max ~16.7M: fits int
  const int lane = tid & 63;
  const int wv   = tid >> 6;

  // ---- (1) weight loads FIRST (oldest vmcnt entries; L2-hot after wave 1)
  f4_t wa[4], wb[4], wc[4];
#pragma unroll
  for (int it = 0; it < 4; ++it) {
    int j4 = (it * 256 + tid) * 4;
    wa[it] = *(const f4_t*)(wvs + j4);
    wb[it] = *(const f4_t*)(wvt + j4);
    wc[it] = *(const f4_t*)(wproj + j4);
  }

  // ---- (2) async x/illu -> LDS, natural [c][p]. 4 insts each per wave;
  // per inst: 64 lanes x 16B = 4 row-segments of 256B -> 8 lines, async.
#pragma unroll
  for (int it = 0; it < 4; ++it) {
    int u = wv * 1024 + it * 256;              // wave-uniform float offset
    int f = u + lane * 4;
    int c = f >> 6, p = f & 63;
    gload16(x + base + c * HW + p, xs + u);
    gload16(illu + base + c * HW + p, ils + u);
  }

  // ---- (3) blend/convert weights (vmcnt wait covers only the 12 oldest
  // loads; the 8 younger async loads stay in flight)
#pragma unroll
  for (int it = 0; it < 4; ++it) {
    int idx = it * 256 + tid;                  // float4 index 0..1023
    int r = idx >> 4, c4 = (idx & 15) * 4;
    s4_t m, w;
#pragma unroll
    for (int j = 0; j < 4; ++j) {
      m[j] = (short)f2bf(0.6f * wa[it][j] + 0.4f * wb[it][j]);
      w[j] = (short)f2bf(wc[it][j]);
    }
    *(s4_t*)(WM + r * SX + c4) = m;
    *(s4_t*)(WP + r * SX + c4) = w;
  }
  __syncthreads();   // drains async loads (vmcnt 0) + publishes WM/WP

  // ---- (4) LDS transpose: xs[c][p] fp32 -> XH[p][c] bf16.
  // reads: fixed c, lanes p consecutive dwords = free; writes: packed b32,
  // stride 34 dwords -> 4-way (1.58x on 8 insts, negligible).
  {
    const int p = tid & 63, cc = (tid >> 6) << 4;   // 16 channels/thread
#pragma unroll
    for (int k = 0; k < 16; k += 2) {
      float f0 = xs[(cc + k) * PT + p];
      float f1 = xs[(cc + k + 1) * PT + p];
      unsigned pk = (unsigned)f2bf(f0) | ((unsigned)f2bf(f1) << 16);
      *(unsigned*)(XH + p * SX + cc + k) = pk;
    }
  }
  __syncthreads();

  const int n15 = lane & 15, q = lane >> 4;
  const int nb  = wv * 16;                     // wave owns pixels nb..nb+15

  // ---- (5) phase 1: u = wmix * x  (A[m=n15][k=q*8+j], B[n=n15][k])
  f4_t acc[4];
#pragma unroll
  for (int i = 0; i < 4; ++i) acc[i] = (f4_t){0.f, 0.f, 0.f, 0.f};
#pragma unroll
  for (int kc = 0; kc < 2; ++kc) {
    s8_t B = ld8(XH + (nb + n15) * SX + kc * 32 + q * 8);
#pragma unroll
    for (int mt = 0; mt < 4; ++mt) {
      s8_t A = ld8(WM + (mt * 16 + n15) * SX + kc * 32 + q * 8);
      acc[mt] = __builtin_amdgcn_mfma_f32_16x16x32_bf16(A, B, acc[mt], 0, 0, 0);
    }
  }

  // ---- (6) gate from ils; write u'^T into XH. Rows nb..nb+15 are read and
  // written only by this wave (same-wave DS ops stay ordered) -> no barrier.
  s4_t uh[4];
#pragma unroll
  for (int mt = 0; mt < 4; ++mt) {
    s4_t h;
#pragma unroll
    for (int r = 0; r < 4; ++r) {
      int c = mt * 16 + q * 4 + r;             // C/D: row c, col nb+n15
      h[r] = (short)f2bf(acc[mt][r] * ils[c * PT + nb + n15]);
    }
    uh[mt] = h;
  }
#pragma unroll
  for (int mt = 0; mt < 4; ++mt)
    *(s4_t*)(XH + (nb + n15) * SX + mt * 16 + q * 4) = uh[mt];

  // ---- (7) phase 2: y = wproj * u'
  f4_t acc2[4];
#pragma unroll
  for (int i = 0; i < 4; ++i) acc2[i] = (f4_t){0.f, 0.f, 0.f, 0.f};
#pragma unroll
  for (int kc = 0; kc < 2; ++kc) {
    s8_t B = ld8(XH + (nb + n15) * SX + kc * 32 + q * 8);
#pragma unroll
    for (int mt = 0; mt < 4; ++mt) {
      s8_t A = ld8(WP + (mt * 16 + n15) * SX + kc * 32 + q * 8);
      acc2[mt] = __builtin_amdgcn_mfma_f32_16x16x32_bf16(A, B, acc2[mt], 0, 0, 0);
    }
  }

  // ---- (8) store (fire-and-forget; 4x64B segments/inst, merges in L2)
#pragma unroll
  for (int mt = 0; mt < 4; ++mt) {
    float* op = out + base + (mt * 16 + q * 4) * HW + nb + n15;
    f4_t a = acc2[mt];
#pragma unroll
    for (int r = 0; r < 4; ++r) op[r * HW] = a[r];
  }
}

extern "C" void kernel_launch(void* const* d_in, const int* in_sizes, int n_in,
                              void* d_out, int out_size, void* d_ws, size_t ws_size,
                              hipStream_t stream) {
  const float* x     = (const float*)d_in[0];   // (4,64,256,256)
  const float* illu  = (const float*)d_in[1];   // (4,64,256,256)
  const float* wvs   = (const float*)d_in[4];   // w_v_spec (64,64)
  const float* wvt   = (const float*)d_in[7];   // w_v_spat (64,64)
  const float* wproj = (const float*)d_in[10];  // w_proj   (64,64)
  float* out = (float*)d_out;

  fused_hsattn<<<4 * (HW / PT), 256, 0, stream>>>(x, illu, wvs, wvt, wproj, out);
}